// Round 3
// baseline (2801.627 us; speedup 1.0000x reference)
//
#include <hip/hip_runtime.h>

// MetaGRU: 3-step MetaLayer GNN, H=64. STEPS hardcoded (problem fixes gru_steps=3).
#define STEPS 3

typedef _Float16 f16;
typedef _Float16 f16x8 __attribute__((ext_vector_type(8)));
typedef _Float16 f16x4 __attribute__((ext_vector_type(4)));
typedef float    f32x4 __attribute__((ext_vector_type(4)));

__device__ __forceinline__ float sigm(float x)   { return 1.f / (1.f + __expf(-x)); }
__device__ __forceinline__ float tanh_f(float x) { return 1.f - 2.f / (__expf(2.f * x) + 1.f); }

__device__ __forceinline__ f32x4 mfma16(f16x8 a, f16x8 b, f32x4 c) {
  return __builtin_amdgcn_mfma_f32_16x16x32_f16(a, b, c, 0, 0, 0);
}

// ---------------- init: counts, copy x/u into out slice 0, convert weights to f16 ----------------
__global__ void init_kernel(const float* __restrict__ x, const float* __restrict__ u,
                            const int* __restrict__ dstI, const int* __restrict__ batchI,
                            float* __restrict__ out, float* __restrict__ degv, float* __restrict__ gcnt,
                            const float* __restrict__ eW, const float* __restrict__ nW,
                            const float* __restrict__ eWih, const float* __restrict__ eWhh,
                            const float* __restrict__ nWih, const float* __restrict__ nWhh,
                            f16* __restrict__ wf, int N, int E, int G)
{
  const int stride = gridDim.x * blockDim.x;
  const int g0 = blockIdx.x * blockDim.x + threadIdx.x;
  for (int i = g0; i < N * 64; i += stride) out[(size_t)(i >> 6) * 256 + (i & 63)] = x[i];
  for (int i = g0; i < G * 64; i += stride) out[(size_t)N * 256 + (size_t)(i >> 6) * 256 + (i & 63)] = u[i];
  for (int i = g0; i < E; i += stride) atomicAdd(&degv[dstI[i]], 1.f);
  for (int i = g0; i < N; i += stride) atomicAdd(&gcnt[batchI[i]], 1.f);
  for (int i = g0; i < 77824; i += stride) {
    const float* s; int off;
    if      (i < 16384) { s = eW;   off = i; }
    else if (i < 28672) { s = nW;   off = i - 16384; }
    else if (i < 40960) { s = eWih; off = i - 28672; }
    else if (i < 53248) { s = eWhh; off = i - 40960; }
    else if (i < 65536) { s = nWih; off = i - 53248; }
    else                { s = nWhh; off = i - 65536; }
    wf[i] = (f16)s[off];
  }
}

// ---------------- fused edge step: e_out = relu(W_e @ [x_s|x_d|h|u_b]); h' = GRU(e_out, h);
// scatter-add h' into node_sum[dst]. One 64-edge tile per block iteration.
// GRU weights (W_ih/W_hh) live in per-lane registers (tile-invariant B-fragments),
// cutting LDS from 123KB to 74KB -> 2 blocks/CU. ----------------
__global__ __launch_bounds__(256, 1) void edge_step_kernel(
    const float* __restrict__ xsl, const float* __restrict__ usl,
    const float* __restrict__ hsrc, float* __restrict__ hdst,
    float* __restrict__ node_sum,
    const int* __restrict__ srcI, const int* __restrict__ dstI, const int* __restrict__ batchI,
    const f16* __restrict__ wB1, const f16* __restrict__ wBih, const f16* __restrict__ wBhh,
    const float* __restrict__ ebias, const float* __restrict__ bih, const float* __restrict__ bhh,
    int E, int ntiles)
{
  extern __shared__ char sm[];
  char* A1  = sm;            // 64 x 256 f16, 512B rows, XOR-swizzled   32768
  char* B1  = sm + 32768;    // edge_W  (64 n-rows x 256 k)             32768
  char* EO  = sm + 65536;    // e_out 64 x 64 f16, 128B rows             8192
  int*  DL  = (int*)(sm + 73728); // dst per tile row                     256

  const int t = threadIdx.x;
  const int lane = t & 63, w = t >> 6;
  const int l15 = lane & 15, lhi = lane >> 4;

  // stage GEMM1 weights (once per block)
  for (int c = t; c < 2048; c += 256) {
    int n = c >> 5, sl = c & 31;
    *(f16x8*)(B1 + n * 512 + ((sl * 16) ^ ((n & 7) << 4))) = *(const f16x8*)(wB1 + n * 256 + sl * 8);
  }
  const int hcol = (w << 4) + l15;                   // this wave's GRU h-column strip
  // GRU weight B-fragments in registers: element offset (g*64+hcol)*64 + kk*32 + lhi*8
  f16x8 biR[3][2], bhR[3][2];
  #pragma unroll
  for (int g = 0; g < 3; g++)
    #pragma unroll
    for (int kk = 0; kk < 2; kk++) {
      const int off = (g * 64 + hcol) * 64 + kk * 32 + (lhi << 3);
      biR[g][kk] = *(const f16x8*)(wBih + off);
      bhR[g][kk] = *(const f16x8*)(wBhh + off);
    }
  const float bihr = bih[hcol], bihz = bih[64 + hcol], bihn = bih[128 + hcol];
  const float bhhr = bhh[hcol], bhhz = bhh[64 + hcol], bhhn = bhh[128 + hcol];
  const int mrow0 = (w & 1) * 32, ncol0 = (w >> 1) * 32;  // GEMM1 quadrant
  const float be0 = ebias[ncol0 + l15], be1 = ebias[ncol0 + 16 + l15];
  __syncthreads();

  for (int tile = blockIdx.x; tile < ntiles; tile += gridDim.x) {
    const int r = t >> 2, q0 = t & 3;
    const int e = tile * 64 + r;
    if (e < E) {
      const int ss = srcI[e], dd = dstI[e];
      const int bb = batchI[ss];
      if (q0 == 0) DL[r] = dd;
      const float* px = xsl + (size_t)ss * 256;
      const float* pd = xsl + (size_t)dd * 256;
      const float* ph = hsrc + (size_t)e * 64;
      const float* pu = usl + (size_t)bb * 256;
      #pragma unroll
      for (int f = q0; f < 64; f += 4) {
        const int seg = f >> 4, part = f & 15;
        const float* p = (seg == 0) ? px : (seg == 1) ? pd : (seg == 2) ? ph : pu;
        float4 v = *(const float4*)(p + part * 4);
        f16x4 h4 = { (f16)v.x, (f16)v.y, (f16)v.z, (f16)v.w };
        *(f16x4*)(A1 + r * 512 + ((f * 8) ^ ((r & 7) << 4))) = h4;
      }
    } else {
      if (q0 == 0) DL[r] = 0;
      f16x4 z4 = {(f16)0.f, (f16)0.f, (f16)0.f, (f16)0.f};
      #pragma unroll
      for (int f = q0; f < 64; f += 4)
        *(f16x4*)(A1 + r * 512 + ((f * 8) ^ ((r & 7) << 4))) = z4;
    }
    __syncthreads();

    // GEMM1: 64x64 = A1(64x256) * B1, this wave does its 32x32 quadrant
    f32x4 c00 = {0.f,0.f,0.f,0.f}, c01 = c00, c10 = c00, c11 = c00;
    const int ar0 = mrow0 + l15, ar1 = ar0 + 16;
    const int bn0 = ncol0 + l15, bn1 = bn0 + 16;
    #pragma unroll
    for (int kk = 0; kk < 8; kk++) {
      const int kb = (kk * 32 + (lhi << 3)) * 2;
      f16x8 a0 = *(const f16x8*)(A1 + ar0 * 512 + (kb ^ ((ar0 & 7) << 4)));
      f16x8 a1 = *(const f16x8*)(A1 + ar1 * 512 + (kb ^ ((ar1 & 7) << 4)));
      f16x8 b0 = *(const f16x8*)(B1 + bn0 * 512 + (kb ^ ((bn0 & 7) << 4)));
      f16x8 b1 = *(const f16x8*)(B1 + bn1 * 512 + (kb ^ ((bn1 & 7) << 4)));
      c00 = mfma16(a0, b0, c00); c01 = mfma16(a0, b1, c01);
      c10 = mfma16(a1, b0, c10); c11 = mfma16(a1, b1, c11);
    }
    {
      const int rb = mrow0 + (lhi << 2);
      const int cb0 = (ncol0 + l15) * 2, cb1 = cb0 + 32;
      #pragma unroll
      for (int j = 0; j < 4; j++) {
        const int row = rb + j, row1 = row + 16;
        *(f16*)(EO + row  * 128 + (cb0 ^ ((row  & 7) << 4))) = (f16)fmaxf(c00[j] + be0, 0.f);
        *(f16*)(EO + row  * 128 + (cb1 ^ ((row  & 7) << 4))) = (f16)fmaxf(c01[j] + be1, 0.f);
        *(f16*)(EO + row1 * 128 + (cb0 ^ ((row1 & 7) << 4))) = (f16)fmaxf(c10[j] + be0, 0.f);
        *(f16*)(EO + row1 * 128 + (cb1 ^ ((row1 & 7) << 4))) = (f16)fmaxf(c11[j] + be1, 0.f);
      }
    }
    __syncthreads();

    // GEMM2: gi = EO @ W_ih^T, gh = h @ W_hh^T ; wave w covers all 64 rows, h-cols [w*16,w*16+16), 3 gates
    f32x4 gi[3][4], gh[3][4];
    #pragma unroll
    for (int g = 0; g < 3; g++)
      #pragma unroll
      for (int mi = 0; mi < 4; mi++) { gi[g][mi] = {0.f,0.f,0.f,0.f}; gh[g][mi] = {0.f,0.f,0.f,0.f}; }
    #pragma unroll
    for (int kk = 0; kk < 2; kk++) {
      const int kb = (kk * 32 + (lhi << 3)) * 2;
      f16x8 ae[4], ah[4];
      #pragma unroll
      for (int mi = 0; mi < 4; mi++) {
        const int row = mi * 16 + l15;
        ae[mi] = *(const f16x8*)(EO + row * 128 + (kb ^ ((row & 7) << 4)));
        ah[mi] = *(const f16x8*)(A1 + row * 512 + ((256 + kb) ^ ((row & 7) << 4)));  // h segment
      }
      #pragma unroll
      for (int g = 0; g < 3; g++) {
        #pragma unroll
        for (int mi = 0; mi < 4; mi++) {
          gi[g][mi] = mfma16(ae[mi], biR[g][kk], gi[g][mi]);
          gh[g][mi] = mfma16(ah[mi], bhR[g][kk], gh[g][mi]);
        }
      }
    }
    // GRU epilogue + scatter
    #pragma unroll
    for (int mi = 0; mi < 4; mi++) {
      const int rb = mi * 16 + (lhi << 2);
      #pragma unroll
      for (int j = 0; j < 4; j++) {
        const int row = rb + j;
        const int e2 = tile * 64 + row;
        if (e2 < E) {
          float rr = sigm(gi[0][mi][j] + bihr + gh[0][mi][j] + bhhr);
          float zz = sigm(gi[1][mi][j] + bihz + gh[1][mi][j] + bhhz);
          float nn = tanh_f(gi[2][mi][j] + bihn + rr * (gh[2][mi][j] + bhhn));
          float hp = hsrc[(size_t)e2 * 64 + hcol];
          float hv = (1.f - zz) * nn + zz * hp;
          hdst[(size_t)e2 * 64 + hcol] = hv;
          atomicAdd(&node_sum[(size_t)DL[row] * 64 + hcol], hv);
        }
      }
    }
    __syncthreads();
  }
}

// ---------------- fused node step: x_out = relu(W_n @ [x|agg|u_b]); x' = GRU(x_out, x);
// writes x' into next out slice, scatter-adds into graph_sum, zeroes node_sum for next step. ----------------
__global__ __launch_bounds__(256, 1) void node_step_kernel(
    const float* __restrict__ xsl, const float* __restrict__ usl,
    float* __restrict__ xdst,
    float* __restrict__ node_sum, const float* __restrict__ degv,
    float* __restrict__ graph_sum, const int* __restrict__ batchI,
    const f16* __restrict__ wB1, const f16* __restrict__ wBih, const f16* __restrict__ wBhh,
    const float* __restrict__ nbias, const float* __restrict__ bih, const float* __restrict__ bhh,
    int N, int ntiles)
{
  extern __shared__ char sm[];
  char* A1  = sm;            // 64 x 192 f16, 384B rows                24576
  char* B1  = sm + 24576;    // node_W (64 x 192)                      24576
  char* EO  = sm + 49152;    //                                         8192
  int*  BL  = (int*)(sm + 57344);

  const int t = threadIdx.x;
  const int lane = t & 63, w = t >> 6;
  const int l15 = lane & 15, lhi = lane >> 4;
  for (int c = t; c < 1536; c += 256) {
    int n = c / 24, sl = c - n * 24;
    *(f16x8*)(B1 + n * 384 + ((sl * 16) ^ ((n & 7) << 4))) = *(const f16x8*)(wB1 + n * 192 + sl * 8);
  }
  const int hcol = (w << 4) + l15;
  f16x8 biR[3][2], bhR[3][2];
  #pragma unroll
  for (int g = 0; g < 3; g++)
    #pragma unroll
    for (int kk = 0; kk < 2; kk++) {
      const int off = (g * 64 + hcol) * 64 + kk * 32 + (lhi << 3);
      biR[g][kk] = *(const f16x8*)(wBih + off);
      bhR[g][kk] = *(const f16x8*)(wBhh + off);
    }
  const float bihr = bih[hcol], bihz = bih[64 + hcol], bihn = bih[128 + hcol];
  const float bhhr = bhh[hcol], bhhz = bhh[64 + hcol], bhhn = bhh[128 + hcol];
  const int mrow0 = (w & 1) * 32, ncol0 = (w >> 1) * 32;
  const float be0 = nbias[ncol0 + l15], be1 = nbias[ncol0 + 16 + l15];
  __syncthreads();

  for (int tile = blockIdx.x; tile < ntiles; tile += gridDim.x) {
    const int r = t >> 2, q0 = t & 3;
    const int nid = tile * 64 + r;
    if (nid < N) {
      const int bb = batchI[nid];
      if (q0 == 0) BL[r] = bb;
      const float dinv = 1.f / fmaxf(degv[nid], 1.f);
      const float* px = xsl + (size_t)nid * 256;
      float*       ps = node_sum + (size_t)nid * 64;
      const float* pu = usl + (size_t)bb * 256;
      #pragma unroll
      for (int f = q0; f < 48; f += 4) {
        const int seg = f >> 4, part = f & 15;
        float4 v;
        if (seg == 0)      v = *(const float4*)(px + part * 4);
        else if (seg == 1) {
          v = *(const float4*)(ps + part * 4);
          v.x *= dinv; v.y *= dinv; v.z *= dinv; v.w *= dinv;
          float4 zz = {0.f, 0.f, 0.f, 0.f};
          *(float4*)(ps + part * 4) = zz;            // zero for next step's atomics
        } else             v = *(const float4*)(pu + part * 4);
        f16x4 h4 = { (f16)v.x, (f16)v.y, (f16)v.z, (f16)v.w };
        *(f16x4*)(A1 + r * 384 + ((f * 8) ^ ((r & 7) << 4))) = h4;
      }
    } else {
      if (q0 == 0) BL[r] = 0;
      f16x4 z4 = {(f16)0.f, (f16)0.f, (f16)0.f, (f16)0.f};
      #pragma unroll
      for (int f = q0; f < 48; f += 4)
        *(f16x4*)(A1 + r * 384 + ((f * 8) ^ ((r & 7) << 4))) = z4;
    }
    __syncthreads();

    f32x4 c00 = {0.f,0.f,0.f,0.f}, c01 = c00, c10 = c00, c11 = c00;
    const int ar0 = mrow0 + l15, ar1 = ar0 + 16;
    const int bn0 = ncol0 + l15, bn1 = bn0 + 16;
    #pragma unroll
    for (int kk = 0; kk < 6; kk++) {
      const int kb = (kk * 32 + (lhi << 3)) * 2;
      f16x8 a0 = *(const f16x8*)(A1 + ar0 * 384 + (kb ^ ((ar0 & 7) << 4)));
      f16x8 a1 = *(const f16x8*)(A1 + ar1 * 384 + (kb ^ ((ar1 & 7) << 4)));
      f16x8 b0 = *(const f16x8*)(B1 + bn0 * 384 + (kb ^ ((bn0 & 7) << 4)));
      f16x8 b1 = *(const f16x8*)(B1 + bn1 * 384 + (kb ^ ((bn1 & 7) << 4)));
      c00 = mfma16(a0, b0, c00); c01 = mfma16(a0, b1, c01);
      c10 = mfma16(a1, b0, c10); c11 = mfma16(a1, b1, c11);
    }
    {
      const int rb = mrow0 + (lhi << 2);
      const int cb0 = (ncol0 + l15) * 2, cb1 = cb0 + 32;
      #pragma unroll
      for (int j = 0; j < 4; j++) {
        const int row = rb + j, row1 = row + 16;
        *(f16*)(EO + row  * 128 + (cb0 ^ ((row  & 7) << 4))) = (f16)fmaxf(c00[j] + be0, 0.f);
        *(f16*)(EO + row  * 128 + (cb1 ^ ((row  & 7) << 4))) = (f16)fmaxf(c01[j] + be1, 0.f);
        *(f16*)(EO + row1 * 128 + (cb0 ^ ((row1 & 7) << 4))) = (f16)fmaxf(c10[j] + be0, 0.f);
        *(f16*)(EO + row1 * 128 + (cb1 ^ ((row1 & 7) << 4))) = (f16)fmaxf(c11[j] + be1, 0.f);
      }
    }
    __syncthreads();

    f32x4 gi[3][4], gh[3][4];
    #pragma unroll
    for (int g = 0; g < 3; g++)
      #pragma unroll
      for (int mi = 0; mi < 4; mi++) { gi[g][mi] = {0.f,0.f,0.f,0.f}; gh[g][mi] = {0.f,0.f,0.f,0.f}; }
    #pragma unroll
    for (int kk = 0; kk < 2; kk++) {
      const int kb = (kk * 32 + (lhi << 3)) * 2;
      f16x8 ae[4], ah[4];
      #pragma unroll
      for (int mi = 0; mi < 4; mi++) {
        const int row = mi * 16 + l15;
        ae[mi] = *(const f16x8*)(EO + row * 128 + (kb ^ ((row & 7) << 4)));
        ah[mi] = *(const f16x8*)(A1 + row * 384 + (kb ^ ((row & 7) << 4)));   // x segment (cols 0..63)
      }
      #pragma unroll
      for (int g = 0; g < 3; g++) {
        #pragma unroll
        for (int mi = 0; mi < 4; mi++) {
          gi[g][mi] = mfma16(ae[mi], biR[g][kk], gi[g][mi]);
          gh[g][mi] = mfma16(ah[mi], bhR[g][kk], gh[g][mi]);
        }
      }
    }
    #pragma unroll
    for (int mi = 0; mi < 4; mi++) {
      const int rb = mi * 16 + (lhi << 2);
      #pragma unroll
      for (int j = 0; j < 4; j++) {
        const int row = rb + j;
        const int n2 = tile * 64 + row;
        if (n2 < N) {
          float rr = sigm(gi[0][mi][j] + bihr + gh[0][mi][j] + bhhr);
          float zz = sigm(gi[1][mi][j] + bihz + gh[1][mi][j] + bhhz);
          float nn = tanh_f(gi[2][mi][j] + bihn + rr * (gh[2][mi][j] + bhhn));
          float xp = xsl[(size_t)n2 * 256 + hcol];
          float xv = (1.f - zz) * nn + zz * xp;
          xdst[(size_t)n2 * 256 + hcol] = xv;
          atomicAdd(&graph_sum[(size_t)BL[row] * 64 + hcol], xv);
        }
      }
    }
    __syncthreads();
  }
}

// ---------------- global step (tiny): one block per graph, f32 vector math ----------------
__global__ __launch_bounds__(64, 1) void glob_step_kernel(
    float* __restrict__ graph_sum, const float* __restrict__ gcnt,
    const float* __restrict__ usl_in, float* __restrict__ usl_out,
    const float* __restrict__ gW, const float* __restrict__ gb,
    const float* __restrict__ gWih, const float* __restrict__ gWhh,
    const float* __restrict__ gbih, const float* __restrict__ gbhh)
{
  __shared__ float gin[128];
  __shared__ float xo[64];
  const int t = threadIdx.x, g = blockIdx.x;
  const float cnt = fmaxf(gcnt[g], 1.f);
  const float mean = graph_sum[g * 64 + t] / cnt;
  graph_sum[g * 64 + t] = 0.f;                 // zero for next step
  const float up = usl_in[(size_t)g * 256 + t];
  gin[t] = mean; gin[64 + t] = up;
  __syncthreads();
  float a0 = 0.f, a1 = 0.f, a2 = 0.f, a3 = 0.f;
  const float* wr = gW + t * 128;
  #pragma unroll 8
  for (int k = 0; k < 128; k += 4) {
    a0 += wr[k] * gin[k]; a1 += wr[k+1] * gin[k+1];
    a2 += wr[k+2] * gin[k+2]; a3 += wr[k+3] * gin[k+3];
  }
  const float uo = fmaxf(a0 + a1 + a2 + a3 + gb[t], 0.f);
  xo[t] = uo;
  __syncthreads();
  float acc[6];
  #pragma unroll
  for (int g3 = 0; g3 < 3; g3++) {
    const float* wi = gWih + (size_t)(g3 * 64 + t) * 64;
    const float* wh = gWhh + (size_t)(g3 * 64 + t) * 64;
    float s0 = 0.f, s1 = 0.f, s2 = 0.f, s3 = 0.f;
    #pragma unroll 8
    for (int k = 0; k < 64; k += 2) {
      s0 += wi[k] * xo[k];       s1 += wi[k+1] * xo[k+1];
      s2 += wh[k] * gin[64+k];   s3 += wh[k+1] * gin[64+k+1];
    }
    acc[g3]     = s0 + s1 + gbih[g3 * 64 + t];
    acc[3 + g3] = s2 + s3 + gbhh[g3 * 64 + t];
  }
  const float r = sigm(acc[0] + acc[3]);
  const float z = sigm(acc[1] + acc[4]);
  const float nn = tanh_f(acc[2] + r * acc[5]);
  usl_out[(size_t)g * 256 + t] = (1.f - z) * nn + z * up;
}

extern "C" void kernel_launch(void* const* d_in, const int* in_sizes, int n_in,
                              void* d_out, int out_size, void* d_ws, size_t ws_size,
                              hipStream_t stream) {
  const float* x    = (const float*)d_in[0];
  const int*  eidx  = (const int*)d_in[1];
  const float* ea   = (const float*)d_in[2];
  const float* u    = (const float*)d_in[3];
  const int*  batch = (const int*)d_in[4];
  const float* eW   = (const float*)d_in[6];
  const float* eb   = (const float*)d_in[7];
  const float* nW   = (const float*)d_in[8];
  const float* nb   = (const float*)d_in[9];
  const float* gW   = (const float*)d_in[10];
  const float* gb   = (const float*)d_in[11];
  const float* eWih = (const float*)d_in[12];
  const float* eWhh = (const float*)d_in[13];
  const float* ebih = (const float*)d_in[14];
  const float* ebhh = (const float*)d_in[15];
  const float* nWih = (const float*)d_in[16];
  const float* nWhh = (const float*)d_in[17];
  const float* nbih = (const float*)d_in[18];
  const float* nbhh = (const float*)d_in[19];
  const float* gWih = (const float*)d_in[20];
  const float* gWhh = (const float*)d_in[21];
  const float* gbih = (const float*)d_in[22];
  const float* gbhh = (const float*)d_in[23];
  (void)n_in; (void)out_size;

  const int N = in_sizes[4];
  const int E = in_sizes[1] / 2;
  const int G = in_sizes[3] / 64;
  const int* srcI = eidx;
  const int* dstI = eidx + E;

  float* out = (float*)d_out;
  char*  ws  = (char*)d_ws;

  const size_t o_deg   = (size_t)N * 64 * 4;
  const size_t o_gcnt  = o_deg + (size_t)N * 4;
  const size_t o_gsum  = o_gcnt + 256;
  const size_t o_wf    = o_gsum + (size_t)G * 64 * 4;
  const size_t o_wf_al = (o_wf + 255) & ~(size_t)255;
  const size_t o_he    = (o_wf_al + (size_t)77824 * 2 + 255) & ~(size_t)255;
  const size_t need    = o_he + (size_t)E * 64 * 4;

  float* node_sum = (float*)ws;
  float* degv = (float*)(ws + o_deg);
  float* gcnt = (float*)(ws + o_gcnt);
  float* gsum = (float*)(ws + o_gsum);
  f16*   wf   = (f16*)(ws + o_wf_al);
  // h ping buffer; if ws is too small, update edge_attr in-place (d_in is restored every launch)
  float* he = (ws_size >= need) ? (float*)(ws + o_he) : (float*)d_in[2];

  hipMemsetAsync(d_ws, 0, o_wf, stream);

  (void)hipFuncSetAttribute((const void*)edge_step_kernel,
                            hipFuncAttributeMaxDynamicSharedMemorySize, 73984);
  (void)hipFuncSetAttribute((const void*)node_step_kernel,
                            hipFuncAttributeMaxDynamicSharedMemorySize, 57600);

  init_kernel<<<2048, 256, 0, stream>>>(x, u, dstI, batch, out, degv, gcnt,
                                        eW, nW, eWih, eWhh, nWih, nWhh, wf, N, E, G);

  const f16* wfB1e = wf;
  const f16* wfB1n = wf + 16384;
  const f16* wfEih = wf + 28672;
  const f16* wfEhh = wf + 40960;
  const f16* wfNih = wf + 53248;
  const f16* wfNhh = wf + 65536;

  const int etiles = (E + 63) / 64;
  const int ntiles = (N + 63) / 64;

  for (int s = 0; s < STEPS; s++) {
    const float* xslice = out + s * 64;
    const float* uslice = out + (size_t)N * 256 + s * 64;
    const float* hs = (s == 0) ? ea : he;
    edge_step_kernel<<<512, 256, 73984, stream>>>(
        xslice, uslice, hs, he, node_sum, srcI, dstI, batch,
        wfB1e, wfEih, wfEhh, eb, ebih, ebhh, E, etiles);
    node_step_kernel<<<256, 256, 57600, stream>>>(
        xslice, uslice, out + (size_t)(s + 1) * 64, node_sum, degv, gsum, batch,
        wfB1n, wfNih, wfNhh, nb, nbih, nbhh, N, ntiles);
    glob_step_kernel<<<G, 64, 0, stream>>>(
        gsum, gcnt, out + (size_t)N * 256 + s * 64, out + (size_t)N * 256 + (size_t)(s + 1) * 64,
        gW, gb, gWih, gWhh, gbih, gbhh);
  }
}

// Round 4
// 2012.056 us; speedup vs baseline: 1.3924x; 1.3924x over previous
//
#include <hip/hip_runtime.h>

// MetaGRU: 3-step MetaLayer GNN, H=64. STEPS hardcoded (problem fixes gru_steps=3).
#define STEPS 3

typedef _Float16 f16;
typedef _Float16 f16x8 __attribute__((ext_vector_type(8)));
typedef _Float16 f16x4 __attribute__((ext_vector_type(4)));
typedef float    f32x4 __attribute__((ext_vector_type(4)));

__device__ __forceinline__ float sigm(float x)   { return 1.f / (1.f + __expf(-x)); }
__device__ __forceinline__ float tanh_f(float x) { return 1.f - 2.f / (__expf(2.f * x) + 1.f); }

__device__ __forceinline__ f32x4 mfma16(f16x8 a, f16x8 b, f32x4 c) {
  return __builtin_amdgcn_mfma_f32_16x16x32_f16(a, b, c, 0, 0, 0);
}

union cv16 { f16x8 h; uint4 u; };

// ---------------- init: counts, copy x/u into out slice 0, f16 compaction, weights to f16 ----------------
__global__ void init_kernel(const float* __restrict__ x, const float* __restrict__ u,
                            const float* __restrict__ ea,
                            const int* __restrict__ dstI, const int* __restrict__ batchI,
                            float* __restrict__ out, float* __restrict__ degv, float* __restrict__ gcnt,
                            const float* __restrict__ eW, const float* __restrict__ nW,
                            const float* __restrict__ eWih, const float* __restrict__ eWhh,
                            const float* __restrict__ nWih, const float* __restrict__ nWhh,
                            f16* __restrict__ wf, f16* __restrict__ xc, f16* __restrict__ uc,
                            f16* he, int cvt_he, int N, int E, int G)
{
  const int stride = gridDim.x * blockDim.x;
  const int g0 = blockIdx.x * blockDim.x + threadIdx.x;
  for (int i = g0; i < N * 64; i += stride) out[(size_t)(i >> 6) * 256 + (i & 63)] = x[i];
  for (int i = g0; i < G * 64; i += stride) out[(size_t)N * 256 + (size_t)(i >> 6) * 256 + (i & 63)] = u[i];
  for (int i = g0; i < E; i += stride) atomicAdd(&degv[dstI[i]], 1.f);
  for (int i = g0; i < N; i += stride) atomicAdd(&gcnt[batchI[i]], 1.f);
  // f16 compaction (vectorized float4 -> f16x4)
  for (int i = g0; i < N * 16; i += stride) {
    float4 v = ((const float4*)x)[i];
    f16x4 h = { (f16)v.x, (f16)v.y, (f16)v.z, (f16)v.w };
    *(f16x4*)(xc + (size_t)i * 4) = h;
  }
  for (int i = g0; i < G * 16; i += stride) {
    float4 v = ((const float4*)u)[i];
    f16x4 h = { (f16)v.x, (f16)v.y, (f16)v.z, (f16)v.w };
    *(f16x4*)(uc + (size_t)i * 4) = h;
  }
  if (cvt_he) {
    for (size_t i = g0; i < (size_t)E * 16; i += stride) {
      float4 v = ((const float4*)ea)[i];
      f16x4 h = { (f16)v.x, (f16)v.y, (f16)v.z, (f16)v.w };
      *(f16x4*)(he + i * 4) = h;
    }
  }
  for (int i = g0; i < 77824; i += stride) {
    const float* s; int off;
    if      (i < 16384) { s = eW;   off = i; }
    else if (i < 28672) { s = nW;   off = i - 16384; }
    else if (i < 40960) { s = eWih; off = i - 28672; }
    else if (i < 53248) { s = eWhh; off = i - 40960; }
    else if (i < 65536) { s = nWih; off = i - 53248; }
    else                { s = nWhh; off = i - 65536; }
    wf[i] = (f16)s[off];
  }
}

// ---------------- fused edge step: e_out = relu(W_e @ [x_s|x_d|h|u_b]); h' = GRU(e_out, h);
// scatter-add h' into node_sum[dst]. Register-prefetched staging (next tile's gathers fly
// under current tile's GEMMs). H16: h state stored as f16 (in-place buffer). ----------------
template<bool H16>
__global__ __launch_bounds__(256, 1) void edge_step_kernel(
    const f16* __restrict__ xc, const f16* __restrict__ uc,
    const void* __restrict__ hsrcv, void* __restrict__ hdstv,
    float* __restrict__ node_sum,
    const int* __restrict__ srcI, const int* __restrict__ dstI, const int* __restrict__ batchI,
    const f16* __restrict__ wB1, const f16* __restrict__ wBih, const f16* __restrict__ wBhh,
    const float* __restrict__ ebias, const float* __restrict__ bih, const float* __restrict__ bhh,
    int E, int ntiles)
{
  extern __shared__ char sm[];
  char* A1  = sm;            // 64 x 256 f16, 512B rows, XOR-swizzled   32768
  char* B1  = sm + 32768;    // edge_W  (64 n-rows x 256 k)             32768
  char* EO  = sm + 65536;    // e_out 64 x 64 f16, 128B rows             8192
  int*  DL  = (int*)(sm + 73728); // dst per tile row                     256

  const f16*   hs16 = (const f16*)hsrcv;
  const float* hs32 = (const float*)hsrcv;

  const int t = threadIdx.x;
  const int lane = t & 63, w = t >> 6;
  const int l15 = lane & 15, lhi = lane >> 4;
  const int r = t >> 2, q0 = t & 3;

  // stage GEMM1 weights (once per block)
  for (int c = t; c < 2048; c += 256) {
    int n = c >> 5, sl = c & 31;
    *(f16x8*)(B1 + n * 512 + ((sl * 16) ^ ((n & 7) << 4))) = *(const f16x8*)(wB1 + n * 256 + sl * 8);
  }
  const int hcol = (w << 4) + l15;                   // this wave's GRU h-column strip
  // GRU weight B-fragments in registers
  f16x8 biR[3][2], bhR[3][2];
  #pragma unroll
  for (int g = 0; g < 3; g++)
    #pragma unroll
    for (int kk = 0; kk < 2; kk++) {
      const int off = (g * 64 + hcol) * 64 + kk * 32 + (lhi << 3);
      biR[g][kk] = *(const f16x8*)(wBih + off);
      bhR[g][kk] = *(const f16x8*)(wBhh + off);
    }
  const float bihr = bih[hcol], bihz = bih[64 + hcol], bihn = bih[128 + hcol];
  const float bhhr = bhh[hcol], bhhz = bhh[64 + hcol], bhhn = bhh[128 + hcol];
  const int mrow0 = (w & 1) * 32, ncol0 = (w >> 1) * 32;  // GEMM1 quadrant
  const float be0 = ebias[ncol0 + l15], be1 = ebias[ncol0 + 16 + l15];

  uint4 pf[8]; int pfDL = 0;

  // issue gathers for a tile into registers (chunk f = q0+4i, 32 chunks of 16B per 256-f16 row)
  auto issue = [&](int tile) {
    const int e = tile * 64 + r;
    if (e < E) {
      const int ss = srcI[e], dd = dstI[e];
      const int bb = batchI[ss];
      pfDL = dd;
      const f16* px = xc + (size_t)ss * 64;
      const f16* pd = xc + (size_t)dd * 64;
      const f16* pu = uc + (size_t)bb * 64;
      #pragma unroll
      for (int i = 0; i < 8; i++) {
        const int f = q0 + i * 4, seg = f >> 3, part = f & 7;
        if (seg == 2) {
          if (H16) pf[i] = *(const uint4*)(hs16 + (size_t)e * 64 + part * 8);
          else {
            const float* ph = hs32 + (size_t)e * 64 + part * 8;
            float4 a = *(const float4*)(ph), b = *(const float4*)(ph + 4);
            cv16 c; c.h = f16x8{ (f16)a.x,(f16)a.y,(f16)a.z,(f16)a.w,
                                 (f16)b.x,(f16)b.y,(f16)b.z,(f16)b.w };
            pf[i] = c.u;
          }
        } else {
          const f16* p = (seg == 0) ? px : (seg == 1) ? pd : pu;
          pf[i] = *(const uint4*)(p + part * 8);
        }
      }
    } else {
      pfDL = 0;
      #pragma unroll
      for (int i = 0; i < 8; i++) pf[i] = uint4{0u, 0u, 0u, 0u};
    }
  };
  auto commit = [&]() {
    if (q0 == 0) DL[r] = pfDL;
    #pragma unroll
    for (int i = 0; i < 8; i++) {
      const int f = q0 + i * 4;
      *(uint4*)(A1 + r * 512 + ((f * 16) ^ ((r & 7) << 4))) = pf[i];
    }
  };

  int tile = blockIdx.x;
  if (tile < ntiles) issue(tile);
  __syncthreads();  // B1 staged

  for (; tile < ntiles; tile += gridDim.x) {
    commit();
    __syncthreads();                       // A1 ready
    const int nt = tile + gridDim.x;
    if (nt < ntiles) issue(nt);            // prefetch flies under GEMMs

    // GEMM1: 64x64 = A1(64x256) * B1, this wave does its 32x32 quadrant
    f32x4 c00 = {0.f,0.f,0.f,0.f}, c01 = c00, c10 = c00, c11 = c00;
    const int ar0 = mrow0 + l15, ar1 = ar0 + 16;
    const int bn0 = ncol0 + l15, bn1 = bn0 + 16;
    #pragma unroll
    for (int kk = 0; kk < 8; kk++) {
      const int kb = (kk * 32 + (lhi << 3)) * 2;
      f16x8 a0 = *(const f16x8*)(A1 + ar0 * 512 + (kb ^ ((ar0 & 7) << 4)));
      f16x8 a1 = *(const f16x8*)(A1 + ar1 * 512 + (kb ^ ((ar1 & 7) << 4)));
      f16x8 b0 = *(const f16x8*)(B1 + bn0 * 512 + (kb ^ ((bn0 & 7) << 4)));
      f16x8 b1 = *(const f16x8*)(B1 + bn1 * 512 + (kb ^ ((bn1 & 7) << 4)));
      c00 = mfma16(a0, b0, c00); c01 = mfma16(a0, b1, c01);
      c10 = mfma16(a1, b0, c10); c11 = mfma16(a1, b1, c11);
    }
    {
      const int rb = mrow0 + (lhi << 2);
      const int cb0 = (ncol0 + l15) * 2, cb1 = cb0 + 32;
      #pragma unroll
      for (int j = 0; j < 4; j++) {
        const int row = rb + j, row1 = row + 16;
        *(f16*)(EO + row  * 128 + (cb0 ^ ((row  & 7) << 4))) = (f16)fmaxf(c00[j] + be0, 0.f);
        *(f16*)(EO + row  * 128 + (cb1 ^ ((row  & 7) << 4))) = (f16)fmaxf(c01[j] + be1, 0.f);
        *(f16*)(EO + row1 * 128 + (cb0 ^ ((row1 & 7) << 4))) = (f16)fmaxf(c10[j] + be0, 0.f);
        *(f16*)(EO + row1 * 128 + (cb1 ^ ((row1 & 7) << 4))) = (f16)fmaxf(c11[j] + be1, 0.f);
      }
    }
    __syncthreads();

    // GEMM2: gi = EO @ W_ih^T, gh = h @ W_hh^T ; wave w covers all 64 rows, h-cols [w*16,+16), 3 gates
    f32x4 gi[3][4], gh[3][4];
    #pragma unroll
    for (int g = 0; g < 3; g++)
      #pragma unroll
      for (int mi = 0; mi < 4; mi++) { gi[g][mi] = {0.f,0.f,0.f,0.f}; gh[g][mi] = {0.f,0.f,0.f,0.f}; }
    #pragma unroll
    for (int kk = 0; kk < 2; kk++) {
      const int kb = (kk * 32 + (lhi << 3)) * 2;
      f16x8 ae[4], ah[4];
      #pragma unroll
      for (int mi = 0; mi < 4; mi++) {
        const int row = mi * 16 + l15;
        ae[mi] = *(const f16x8*)(EO + row * 128 + (kb ^ ((row & 7) << 4)));
        ah[mi] = *(const f16x8*)(A1 + row * 512 + ((256 + kb) ^ ((row & 7) << 4)));  // h segment
      }
      #pragma unroll
      for (int g = 0; g < 3; g++) {
        #pragma unroll
        for (int mi = 0; mi < 4; mi++) {
          gi[g][mi] = mfma16(ae[mi], biR[g][kk], gi[g][mi]);
          gh[g][mi] = mfma16(ah[mi], bhR[g][kk], gh[g][mi]);
        }
      }
    }
    // GRU epilogue + scatter (h_prev read from LDS A1 h-segment)
    const int hpb = 256 + ((hcol >> 3) << 4);
    const int hpo = (hcol & 7) * 2;
    #pragma unroll
    for (int mi = 0; mi < 4; mi++) {
      const int rb = mi * 16 + (lhi << 2);
      #pragma unroll
      for (int j = 0; j < 4; j++) {
        const int row = rb + j;
        const int e2 = tile * 64 + row;
        if (e2 < E) {
          float rr = sigm(gi[0][mi][j] + bihr + gh[0][mi][j] + bhhr);
          float zz = sigm(gi[1][mi][j] + bihz + gh[1][mi][j] + bhhz);
          float nn = tanh_f(gi[2][mi][j] + bihn + rr * (gh[2][mi][j] + bhhn));
          float hp = (float)*(const f16*)(A1 + row * 512 + (hpb ^ ((row & 7) << 4)) + hpo);
          float hv = (1.f - zz) * nn + zz * hp;
          if (H16) ((f16*)hdstv)[(size_t)e2 * 64 + hcol] = (f16)hv;
          else     ((float*)hdstv)[(size_t)e2 * 64 + hcol] = hv;
          atomicAdd(&node_sum[(size_t)DL[row] * 64 + hcol], hv);
        }
      }
    }
    __syncthreads();
  }
}

// ---------------- fused node step: x_out = relu(W_n @ [x|agg|u_b]); x' = GRU(x_out, x);
// writes x' to out slice + compact f16 buffer, scatter-adds into graph_sum, zeroes node_sum. ----------------
__global__ __launch_bounds__(256, 1) void node_step_kernel(
    const f16* __restrict__ xc, const f16* __restrict__ uc,
    const float* __restrict__ xsl, float* __restrict__ xdst, f16* __restrict__ xcw,
    float* __restrict__ node_sum, const float* __restrict__ degv,
    float* __restrict__ graph_sum, const int* __restrict__ batchI,
    const f16* __restrict__ wB1, const f16* __restrict__ wBih, const f16* __restrict__ wBhh,
    const float* __restrict__ nbias, const float* __restrict__ bih, const float* __restrict__ bhh,
    int N, int ntiles)
{
  extern __shared__ char sm[];
  char* A1  = sm;            // 64 x 192 f16, 384B rows                24576
  char* B1  = sm + 24576;    // node_W (64 x 192)                      24576
  char* EO  = sm + 49152;    //                                         8192
  int*  BL  = (int*)(sm + 57344);

  const int t = threadIdx.x;
  const int lane = t & 63, w = t >> 6;
  const int l15 = lane & 15, lhi = lane >> 4;
  for (int c = t; c < 1536; c += 256) {
    int n = c / 24, sl = c - n * 24;
    *(f16x8*)(B1 + n * 384 + ((sl * 16) ^ ((n & 7) << 4))) = *(const f16x8*)(wB1 + n * 192 + sl * 8);
  }
  const int hcol = (w << 4) + l15;
  f16x8 biR[3][2], bhR[3][2];
  #pragma unroll
  for (int g = 0; g < 3; g++)
    #pragma unroll
    for (int kk = 0; kk < 2; kk++) {
      const int off = (g * 64 + hcol) * 64 + kk * 32 + (lhi << 3);
      biR[g][kk] = *(const f16x8*)(wBih + off);
      bhR[g][kk] = *(const f16x8*)(wBhh + off);
    }
  const float bihr = bih[hcol], bihz = bih[64 + hcol], bihn = bih[128 + hcol];
  const float bhhr = bhh[hcol], bhhz = bhh[64 + hcol], bhhn = bhh[128 + hcol];
  const int mrow0 = (w & 1) * 32, ncol0 = (w >> 1) * 32;
  const float be0 = nbias[ncol0 + l15], be1 = nbias[ncol0 + 16 + l15];
  __syncthreads();

  for (int tile = blockIdx.x; tile < ntiles; tile += gridDim.x) {
    const int r = t >> 2, q0 = t & 3;
    const int nid = tile * 64 + r;
    if (nid < N) {
      const int bb = batchI[nid];
      if (q0 == 0) BL[r] = bb;
      const float dinv = 1.f / fmaxf(degv[nid], 1.f);
      const f16* px = xc + (size_t)nid * 64;
      float*     ps = node_sum + (size_t)nid * 64;
      const f16* pu = uc + (size_t)bb * 64;
      #pragma unroll
      for (int f = q0; f < 24; f += 4) {
        uint4 v;
        if (f < 8)       v = *(const uint4*)(px + f * 8);
        else if (f < 16) {
          float4 a = *(const float4*)(ps + (f - 8) * 8);
          float4 b = *(const float4*)(ps + (f - 8) * 8 + 4);
          cv16 c; c.h = f16x8{ (f16)(a.x*dinv),(f16)(a.y*dinv),(f16)(a.z*dinv),(f16)(a.w*dinv),
                               (f16)(b.x*dinv),(f16)(b.y*dinv),(f16)(b.z*dinv),(f16)(b.w*dinv) };
          v = c.u;
          float4 zz = {0.f, 0.f, 0.f, 0.f};
          *(float4*)(ps + (f - 8) * 8) = zz;
          *(float4*)(ps + (f - 8) * 8 + 4) = zz;   // zero for next step's atomics
        } else           v = *(const uint4*)(pu + (f - 16) * 8);
        *(uint4*)(A1 + r * 384 + ((f * 16) ^ ((r & 7) << 4))) = v;
      }
    } else {
      if (q0 == 0) BL[r] = 0;
      #pragma unroll
      for (int f = q0; f < 24; f += 4) {
        uint4 z4 = {0u, 0u, 0u, 0u};
        *(uint4*)(A1 + r * 384 + ((f * 16) ^ ((r & 7) << 4))) = z4;
      }
    }
    __syncthreads();

    f32x4 c00 = {0.f,0.f,0.f,0.f}, c01 = c00, c10 = c00, c11 = c00;
    const int ar0 = mrow0 + l15, ar1 = ar0 + 16;
    const int bn0 = ncol0 + l15, bn1 = bn0 + 16;
    #pragma unroll
    for (int kk = 0; kk < 6; kk++) {
      const int kb = (kk * 32 + (lhi << 3)) * 2;
      f16x8 a0 = *(const f16x8*)(A1 + ar0 * 384 + (kb ^ ((ar0 & 7) << 4)));
      f16x8 a1 = *(const f16x8*)(A1 + ar1 * 384 + (kb ^ ((ar1 & 7) << 4)));
      f16x8 b0 = *(const f16x8*)(B1 + bn0 * 384 + (kb ^ ((bn0 & 7) << 4)));
      f16x8 b1 = *(const f16x8*)(B1 + bn1 * 384 + (kb ^ ((bn1 & 7) << 4)));
      c00 = mfma16(a0, b0, c00); c01 = mfma16(a0, b1, c01);
      c10 = mfma16(a1, b0, c10); c11 = mfma16(a1, b1, c11);
    }
    {
      const int rb = mrow0 + (lhi << 2);
      const int cb0 = (ncol0 + l15) * 2, cb1 = cb0 + 32;
      #pragma unroll
      for (int j = 0; j < 4; j++) {
        const int row = rb + j, row1 = row + 16;
        *(f16*)(EO + row  * 128 + (cb0 ^ ((row  & 7) << 4))) = (f16)fmaxf(c00[j] + be0, 0.f);
        *(f16*)(EO + row  * 128 + (cb1 ^ ((row  & 7) << 4))) = (f16)fmaxf(c01[j] + be1, 0.f);
        *(f16*)(EO + row1 * 128 + (cb0 ^ ((row1 & 7) << 4))) = (f16)fmaxf(c10[j] + be0, 0.f);
        *(f16*)(EO + row1 * 128 + (cb1 ^ ((row1 & 7) << 4))) = (f16)fmaxf(c11[j] + be1, 0.f);
      }
    }
    __syncthreads();

    f32x4 gi[3][4], gh[3][4];
    #pragma unroll
    for (int g = 0; g < 3; g++)
      #pragma unroll
      for (int mi = 0; mi < 4; mi++) { gi[g][mi] = {0.f,0.f,0.f,0.f}; gh[g][mi] = {0.f,0.f,0.f,0.f}; }
    #pragma unroll
    for (int kk = 0; kk < 2; kk++) {
      const int kb = (kk * 32 + (lhi << 3)) * 2;
      f16x8 ae[4], ah[4];
      #pragma unroll
      for (int mi = 0; mi < 4; mi++) {
        const int row = mi * 16 + l15;
        ae[mi] = *(const f16x8*)(EO + row * 128 + (kb ^ ((row & 7) << 4)));
        ah[mi] = *(const f16x8*)(A1 + row * 384 + (kb ^ ((row & 7) << 4)));   // x segment
      }
      #pragma unroll
      for (int g = 0; g < 3; g++) {
        #pragma unroll
        for (int mi = 0; mi < 4; mi++) {
          gi[g][mi] = mfma16(ae[mi], biR[g][kk], gi[g][mi]);
          gh[g][mi] = mfma16(ah[mi], bhR[g][kk], gh[g][mi]);
        }
      }
    }
    #pragma unroll
    for (int mi = 0; mi < 4; mi++) {
      const int rb = mi * 16 + (lhi << 2);
      #pragma unroll
      for (int j = 0; j < 4; j++) {
        const int row = rb + j;
        const int n2 = tile * 64 + row;
        if (n2 < N) {
          float rr = sigm(gi[0][mi][j] + bihr + gh[0][mi][j] + bhhr);
          float zz = sigm(gi[1][mi][j] + bihz + gh[1][mi][j] + bhhz);
          float nn = tanh_f(gi[2][mi][j] + bihn + rr * (gh[2][mi][j] + bhhn));
          float xp = xsl[(size_t)n2 * 256 + hcol];
          float xv = (1.f - zz) * nn + zz * xp;
          xdst[(size_t)n2 * 256 + hcol] = xv;
          xcw[(size_t)n2 * 64 + hcol] = (f16)xv;
          atomicAdd(&graph_sum[(size_t)BL[row] * 64 + hcol], xv);
        }
      }
    }
    __syncthreads();
  }
}

// ---------------- global step (tiny): one block per graph, f32 vector math ----------------
__global__ __launch_bounds__(64, 1) void glob_step_kernel(
    float* __restrict__ graph_sum, const float* __restrict__ gcnt,
    const float* __restrict__ usl_in, float* __restrict__ usl_out, f16* __restrict__ ucw,
    const float* __restrict__ gW, const float* __restrict__ gb,
    const float* __restrict__ gWih, const float* __restrict__ gWhh,
    const float* __restrict__ gbih, const float* __restrict__ gbhh)
{
  __shared__ float gin[128];
  __shared__ float xo[64];
  const int t = threadIdx.x, g = blockIdx.x;
  const float cnt = fmaxf(gcnt[g], 1.f);
  const float mean = graph_sum[g * 64 + t] / cnt;
  graph_sum[g * 64 + t] = 0.f;                 // zero for next step
  const float up = usl_in[(size_t)g * 256 + t];
  gin[t] = mean; gin[64 + t] = up;
  __syncthreads();
  float a0 = 0.f, a1 = 0.f, a2 = 0.f, a3 = 0.f;
  const float* wr = gW + t * 128;
  #pragma unroll 8
  for (int k = 0; k < 128; k += 4) {
    a0 += wr[k] * gin[k]; a1 += wr[k+1] * gin[k+1];
    a2 += wr[k+2] * gin[k+2]; a3 += wr[k+3] * gin[k+3];
  }
  const float uo = fmaxf(a0 + a1 + a2 + a3 + gb[t], 0.f);
  xo[t] = uo;
  __syncthreads();
  float acc[6];
  #pragma unroll
  for (int g3 = 0; g3 < 3; g3++) {
    const float* wi = gWih + (size_t)(g3 * 64 + t) * 64;
    const float* wh = gWhh + (size_t)(g3 * 64 + t) * 64;
    float s0 = 0.f, s1 = 0.f, s2 = 0.f, s3 = 0.f;
    #pragma unroll 8
    for (int k = 0; k < 64; k += 2) {
      s0 += wi[k] * xo[k];       s1 += wi[k+1] * xo[k+1];
      s2 += wh[k] * gin[64+k];   s3 += wh[k+1] * gin[64+k+1];
    }
    acc[g3]     = s0 + s1 + gbih[g3 * 64 + t];
    acc[3 + g3] = s2 + s3 + gbhh[g3 * 64 + t];
  }
  const float r = sigm(acc[0] + acc[3]);
  const float z = sigm(acc[1] + acc[4]);
  const float nn = tanh_f(acc[2] + r * acc[5]);
  const float un = (1.f - z) * nn + z * up;
  usl_out[(size_t)g * 256 + t] = un;
  ucw[(size_t)g * 64 + t] = (f16)un;
}

extern "C" void kernel_launch(void* const* d_in, const int* in_sizes, int n_in,
                              void* d_out, int out_size, void* d_ws, size_t ws_size,
                              hipStream_t stream) {
  const float* x    = (const float*)d_in[0];
  const int*  eidx  = (const int*)d_in[1];
  const float* ea   = (const float*)d_in[2];
  const float* u    = (const float*)d_in[3];
  const int*  batch = (const int*)d_in[4];
  const float* eW   = (const float*)d_in[6];
  const float* eb   = (const float*)d_in[7];
  const float* nW   = (const float*)d_in[8];
  const float* nb   = (const float*)d_in[9];
  const float* gW   = (const float*)d_in[10];
  const float* gb   = (const float*)d_in[11];
  const float* eWih = (const float*)d_in[12];
  const float* eWhh = (const float*)d_in[13];
  const float* ebih = (const float*)d_in[14];
  const float* ebhh = (const float*)d_in[15];
  const float* nWih = (const float*)d_in[16];
  const float* nWhh = (const float*)d_in[17];
  const float* nbih = (const float*)d_in[18];
  const float* nbhh = (const float*)d_in[19];
  const float* gWih = (const float*)d_in[20];
  const float* gWhh = (const float*)d_in[21];
  const float* gbih = (const float*)d_in[22];
  const float* gbhh = (const float*)d_in[23];
  (void)n_in; (void)out_size;

  const int N = in_sizes[4];
  const int E = in_sizes[1] / 2;
  const int G = in_sizes[3] / 64;
  const int* srcI = eidx;
  const int* dstI = eidx + E;

  float* out = (float*)d_out;
  char*  ws  = (char*)d_ws;

  const size_t o_deg   = (size_t)N * 64 * 4;
  const size_t o_gcnt  = o_deg + (size_t)N * 4;
  const size_t o_gsum  = o_gcnt + 256;
  const size_t o_wf    = o_gsum + (size_t)G * 64 * 4;           // zeroed region ends here
  const size_t o_wf_al = (o_wf + 255) & ~(size_t)255;
  const size_t o_xc    = (o_wf_al + (size_t)77824 * 2 + 255) & ~(size_t)255;
  const size_t o_uc    = o_xc + (size_t)N * 64 * 2;
  const size_t o_he    = (o_uc + (size_t)G * 64 * 2 + 255) & ~(size_t)255;
  const size_t need    = o_he + (size_t)E * 64 * 2;

  float* node_sum = (float*)ws;
  float* degv = (float*)(ws + o_deg);
  float* gcnt = (float*)(ws + o_gcnt);
  float* gsum = (float*)(ws + o_gsum);
  f16*   wf   = (f16*)(ws + o_wf_al);
  f16*   xc   = (f16*)(ws + o_xc);
  f16*   uc   = (f16*)(ws + o_uc);
  const bool h16 = (ws_size >= need);
  f16*   he   = h16 ? (f16*)(ws + o_he) : (f16*)nullptr;

  hipMemsetAsync(d_ws, 0, o_wf, stream);

  (void)hipFuncSetAttribute((const void*)edge_step_kernel<true>,
                            hipFuncAttributeMaxDynamicSharedMemorySize, 73984);
  (void)hipFuncSetAttribute((const void*)edge_step_kernel<false>,
                            hipFuncAttributeMaxDynamicSharedMemorySize, 73984);
  (void)hipFuncSetAttribute((const void*)node_step_kernel,
                            hipFuncAttributeMaxDynamicSharedMemorySize, 57600);

  init_kernel<<<2048, 256, 0, stream>>>(x, u, ea, dstI, batch, out, degv, gcnt,
                                        eW, nW, eWih, eWhh, nWih, nWhh,
                                        wf, xc, uc, he, h16 ? 1 : 0, N, E, G);

  const f16* wfB1e = wf;
  const f16* wfB1n = wf + 16384;
  const f16* wfEih = wf + 28672;
  const f16* wfEhh = wf + 40960;
  const f16* wfNih = wf + 53248;
  const f16* wfNhh = wf + 65536;

  const int etiles = (E + 63) / 64;
  const int ntiles = (N + 63) / 64;

  for (int s = 0; s < STEPS; s++) {
    const float* xslice = out + s * 64;
    const float* uslice = out + (size_t)N * 256 + s * 64;
    if (h16) {
      edge_step_kernel<true><<<512, 256, 73984, stream>>>(
          xc, uc, (const void*)he, (void*)he, node_sum, srcI, dstI, batch,
          wfB1e, wfEih, wfEhh, eb, ebih, ebhh, E, etiles);
    } else {
      // in-place f32 h state in d_in[2] (restored by harness each launch)
      edge_step_kernel<false><<<512, 256, 73984, stream>>>(
          xc, uc, (const void*)ea, (void*)ea, node_sum, srcI, dstI, batch,
          wfB1e, wfEih, wfEhh, eb, ebih, ebhh, E, etiles);
    }
    node_step_kernel<<<512, 256, 57600, stream>>>(
        xc, uc, xslice, out + (size_t)(s + 1) * 64, xc, node_sum, degv, gsum, batch,
        wfB1n, wfNih, wfNhh, nb, nbih, nbhh, N, ntiles);
    glob_step_kernel<<<G, 64, 0, stream>>>(
        gsum, gcnt, uslice, out + (size_t)N * 256 + (size_t)(s + 1) * 64, uc,
        gW, gb, gWih, gWhh, gbih, gbhh);
  }
}